// Round 8
// baseline (7528.213 us; speedup 1.0000x reference)
//
#include <hip/hip_runtime.h>
#include <hip/hip_bf16.h>
#include <cmath>

#define LSEQ 256
#define BB   128
#define DD   2048
#define HH   2048
#define BH   (BB*HH)
#define NBLK 256   // persistent scan grid: <= #CUs (256) for guaranteed residency

typedef __attribute__((ext_vector_type(8))) short short8;   // 8 bf16
typedef __attribute__((ext_vector_type(4))) short short4v;  // 4 bf16
typedef __attribute__((ext_vector_type(4))) float f32x4;

// fp32 -> bf16 hi/lo truncation split; hi*hi + hi*lo + lo*hi ~ 2^-16 rel.
__device__ __forceinline__ void split2(float x, short& hi, short& lo) {
    unsigned u = __float_as_uint(x);
    hi = (short)(u >> 16);
    float r = x - __uint_as_float(u & 0xffff0000u);
    lo = (short)(__float_as_uint(r) >> 16);
}

#define MFMA(a, b, c) __builtin_amdgcn_mfma_f32_16x16x32_bf16((a), (b), (c), 0, 0, 0)

// 16B coherent load from the h exchange planes: two relaxed AGENT-scope 8B
// atomic loads -> global_load_dwordx2 sc1 (bypass L1/L2, served by L3).
__device__ __forceinline__ short8 load_h16(const short* p) {
    unsigned long long u0 = __hip_atomic_load((const unsigned long long*)p,
                                              __ATOMIC_RELAXED, __HIP_MEMORY_SCOPE_AGENT);
    unsigned long long u1 = __hip_atomic_load((const unsigned long long*)(p + 4),
                                              __ATOMIC_RELAXED, __HIP_MEMORY_SCOPE_AGENT);
    union { unsigned long long u[2]; short8 s; } r;
    r.u[0] = u0; r.u[1] = u1;
    return r.s;
}

// 8B sc1 store (write-through to L3; keeps L2 clean so the per-step release
// wbl2 has ~nothing to write back).
__device__ __forceinline__ void store8c(void* p, unsigned long long v) {
    __hip_atomic_store((unsigned long long*)p, v, __ATOMIC_RELAXED, __HIP_MEMORY_SCOPE_AGENT);
}
__device__ __forceinline__ unsigned long long packf2(float a, float b) {
    union { float f[2]; unsigned long long u; } r;
    r.f[0] = a; r.f[1] = b;
    return r.u;
}

// ---------------------------------------------------------------------------
// Prep: W [2048][2048] fp32 (k-major) -> outH/outL [n][k] bf16 planes.
// ---------------------------------------------------------------------------
__global__ __launch_bounds__(256) void transpose_split(const float* __restrict__ W,
                                                       short* __restrict__ outH,
                                                       short* __restrict__ outL) {
    __shared__ float S[64][65];
    const int tid = threadIdx.x;
    const int r0 = blockIdx.x * 64;   // k tile
    const int c0 = blockIdx.y * 64;   // n tile
    const int lr = tid >> 2;          // 0..63
    const int lc = (tid & 3) * 16;
#pragma unroll
    for (int j = 0; j < 4; ++j) {
        f32x4 v = *(const f32x4*)&W[(size_t)(r0 + lr) * DD + c0 + lc + 4*j];
#pragma unroll
        for (int q = 0; q < 4; ++q) S[lr][lc + 4*j + q] = v[q];
    }
    __syncthreads();
    short8 h8[2], l8[2];
#pragma unroll
    for (int j = 0; j < 16; ++j) {
        short h, l;
        split2(S[lc + j][lr], h, l);
        h8[j >> 3][j & 7] = h; l8[j >> 3][j & 7] = l;
    }
    const size_t o = (size_t)(c0 + lr) * DD + r0 + lc;
    *(short8*)&outH[o]     = h8[0];
    *(short8*)&outH[o + 8] = h8[1];
    *(short8*)&outL[o]     = l8[0];
    *(short8*)&outL[o + 8] = l8[1];
}

// ---------------------------------------------------------------------------
// xp = X @ W_ih + b  (split-3 bf16 GEMM). 128x128 tile, 4 waves (2x2).
// rt==0 blocks fuse tanh + h0-plane emit.
// ---------------------------------------------------------------------------
__global__ __launch_bounds__(256) void xp_gemm(const float* __restrict__ X,
                                               const short* __restrict__ WTh,
                                               const short* __restrict__ WTl,
                                               const float* __restrict__ bias,
                                               float* __restrict__ C,
                                               short* __restrict__ h0H,
                                               short* __restrict__ h0L) {
    __shared__ short Ah_s[128 * 40];
    __shared__ short Al_s[128 * 40];

    const int tid = threadIdx.x, lane = tid & 63, wave = tid >> 6;
    const int l15 = lane & 15, lg = lane >> 4;

    const int gid = blockIdx.x;
    const int rt = ((gid >> 8) << 4) | (gid & 15);
    const int ct = (gid >> 4) & 15;
    const int row0 = rt * 128, col0 = ct * 128;
    const int wm = (wave >> 1) * 64, wn = (wave & 1) * 64;

    const int sr = tid >> 3, sc = (tid & 7) * 4;
    const float* gA = X + (size_t)(row0 + sr) * DD + sc;

    size_t brow[4];
#pragma unroll
    for (int n = 0; n < 4; ++n)
        brow[n] = (size_t)(col0 + wn + n * 16 + l15) * DD + lg * 8;

    f32x4 acc[4][4] = {};

    for (int k0 = 0; k0 < DD; k0 += 32) {
        f32x4 av[4];
        short4v h4[4], l4[4];
#pragma unroll
        for (int i = 0; i < 4; ++i)
            av[i] = *(const f32x4*)(gA + (size_t)(32 * i) * DD + k0);
#pragma unroll
        for (int i = 0; i < 4; ++i)
#pragma unroll
            for (int q = 0; q < 4; ++q) {
                short h, l; split2(av[i][q], h, l);
                h4[i][q] = h; l4[i][q] = l;
            }
        short8 bh[4], bl[4];
#pragma unroll
        for (int n = 0; n < 4; ++n) {
            bh[n] = *(const short8*)&WTh[brow[n] + k0];
            bl[n] = *(const short8*)&WTl[brow[n] + k0];
        }
        __syncthreads();
#pragma unroll
        for (int i = 0; i < 4; ++i) {
            *(short4v*)&Ah_s[(sr + 32 * i) * 40 + sc] = h4[i];
            *(short4v*)&Al_s[(sr + 32 * i) * 40 + sc] = l4[i];
        }
        __syncthreads();
        short8 ah[4], al[4];
#pragma unroll
        for (int m = 0; m < 4; ++m) {
            const int ro = (wm + m * 16 + l15) * 40 + lg * 8;
            ah[m] = *(const short8*)&Ah_s[ro];
            al[m] = *(const short8*)&Al_s[ro];
        }
#pragma unroll
        for (int m = 0; m < 4; ++m)
#pragma unroll
            for (int n = 0; n < 4; ++n) {
                acc[m][n] = MFMA(ah[m], bh[n], acc[m][n]);
                acc[m][n] = MFMA(ah[m], bl[n], acc[m][n]);
                acc[m][n] = MFMA(al[m], bh[n], acc[m][n]);
            }
    }

    float bv[4];
#pragma unroll
    for (int n = 0; n < 4; ++n) bv[n] = bias[col0 + wn + n * 16 + l15];

    if (rt == 0) {
#pragma unroll
        for (int m = 0; m < 4; ++m)
#pragma unroll
            for (int n = 0; n < 4; ++n)
#pragma unroll
                for (int i = 0; i < 4; ++i) {
                    const int row = wm + m * 16 + lg * 4 + i;
                    const int col = col0 + wn + n * 16 + l15;
                    const float t = tanhf(acc[m][n][i] + bv[n]);
                    const size_t o = (size_t)row * HH + col;
                    C[o] = t;
                    short h, l; split2(t, h, l);
                    h0H[o] = h; h0L[o] = l;
                }
    } else {
#pragma unroll
        for (int m = 0; m < 4; ++m)
#pragma unroll
            for (int n = 0; n < 4; ++n)
#pragma unroll
                for (int i = 0; i < 4; ++i) {
                    const int row = row0 + wm + m * 16 + lg * 4 + i;
                    const int col = col0 + wn + n * 16 + l15;
                    C[(size_t)row * HH + col] = acc[m][n][i] + bv[n];
                }
    }
}

// ---------------------------------------------------------------------------
// Persistent scan (R7 batched-load structure) with a CORRECT release barrier:
//  - producer counter increment is __ATOMIC_RELEASE (emits wbl2 sc1 +
//    vmcnt(0): h-plane sc1 stores are guaranteed at the L3 coherence point
//    BEFORE the counter bump is visible) — closes the R5/R6/R7 race window.
//  - NO acquire/buffer_inv anywhere: consumers read h via sc1 loads that
//    bypass L1/L2, so W/xp L2 residency is never invalidated.
//  - out/final_state stores are sc1 too, keeping L2 clean so the per-step
//    release wbl2 has (nearly) nothing to write back.
// ---------------------------------------------------------------------------
__global__ __launch_bounds__(512) void rnn_scan(const short* __restrict__ WTh,
                                                const short* __restrict__ WTl,
                                                short* __restrict__ hA_hi, short* __restrict__ hA_lo,
                                                short* __restrict__ hB_hi, short* __restrict__ hB_lo,
                                                float* __restrict__ out,
                                                float* __restrict__ final_state,
                                                unsigned* __restrict__ bar) {
    __shared__ short Whi[32 * 2048];    // 128 KB: W-hi strip, swizzled
    __shared__ float red[4][1024];      // 16 KB: cross-wave reduce

    const int tid = threadIdx.x, lane = tid & 63, wave = tid >> 6;
    const int l15 = lane & 15, lg = lane >> 4;
    const int mr = blockIdx.x >> 6, nc = blockIdx.x & 63;
    const int m0 = mr * 32, n0 = nc * 32;
    unsigned* grp_cnt = bar + mr * 64;  // 256B apart per mr group

    // one-time LDS fill of W-hi strip (swizzle: byte ^= (col&7)<<4)
    for (int it = 0; it < 16; ++it) {
        const int ci  = it * 512 + tid;   // 8192 16B-chunks
        const int col = ci >> 8;          // 0..31
        const int kc  = ci & 255;
        const short8 v = *(const short8*)&WTh[(size_t)(n0 + col) * HH + kc * 8];
        const int byte = ((col << 12) + (kc << 4)) ^ ((col & 7) << 4);
        *(short8*)((char*)Whi + byte) = v;
    }
    __syncthreads();

    const size_t a0 = (size_t)(m0 + l15) * HH;
    const size_t a1 = a0 + (size_t)16 * HH;
    const size_t b0 = (size_t)(n0 + l15) * HH;
    const size_t b1 = b0 + (size_t)16 * HH;
    const int kbase = wave * 256 + lg * 8;
    const int colbase0 = l15 << 12,        swz0 = (l15 & 7) << 4;
    const int colbase1 = (16 + l15) << 12, swz1 = (l15 & 7) << 4;

    const int e = tid * 2, er = e >> 5, ec = e & 31;       // epilogue coords
    const size_t po = (size_t)(m0 + er) * HH + n0 + ec;

    for (int t = 1; t < LSEQ; ++t) {
        const short* hHp = (t & 1) ? hA_hi : hB_hi;   // parity of t-1
        const short* hLp = (t & 1) ? hA_lo : hB_lo;
        short* oH = (t & 1) ? hB_hi : hA_hi;
        short* oL = (t & 1) ? hB_lo : hA_lo;
        float* io = out + (size_t)t * BH;

        // ---- phase 1: batch-issue ALL loads (xp, h chunks, W-lo) ----
        const float2 xv = *(const float2*)(io + po);
        short8 AH0[8], AH1[8], AL0[8], AL1[8], BL0[8], BL1[8];
#pragma unroll
        for (int kt = 0; kt < 8; ++kt) {
            const int k = kbase + kt * 32;
            AH0[kt] = load_h16(&hHp[a0 + k]);
            AH1[kt] = load_h16(&hHp[a1 + k]);
            AL0[kt] = load_h16(&hLp[a0 + k]);
            AL1[kt] = load_h16(&hLp[a1 + k]);
            BL0[kt] = *(const short8*)&WTl[b0 + k];
            BL1[kt] = *(const short8*)&WTl[b1 + k];
        }

        // ---- phase 2: MFMA chain (vmcnt waits resolve per-kt, FIFO) ----
        f32x4 acc00 = {}, acc01 = {}, acc10 = {}, acc11 = {};
#pragma unroll
        for (int kt = 0; kt < 8; ++kt) {
            const int k = kbase + kt * 32;
            const short8 bh0 = *(const short8*)((const char*)Whi + (colbase0 | ((2 * k) ^ swz0)));
            const short8 bh1 = *(const short8*)((const char*)Whi + (colbase1 | ((2 * k) ^ swz1)));
            acc00 = MFMA(AH0[kt], bh0, acc00); acc00 = MFMA(AH0[kt], BL0[kt], acc00); acc00 = MFMA(AL0[kt], bh0, acc00);
            acc01 = MFMA(AH0[kt], bh1, acc01); acc01 = MFMA(AH0[kt], BL1[kt], acc01); acc01 = MFMA(AL0[kt], bh1, acc01);
            acc10 = MFMA(AH1[kt], bh0, acc10); acc10 = MFMA(AH1[kt], BL0[kt], acc10); acc10 = MFMA(AL1[kt], bh0, acc10);
            acc11 = MFMA(AH1[kt], bh1, acc11); acc11 = MFMA(AH1[kt], BL1[kt], acc11); acc11 = MFMA(AL1[kt], bh1, acc11);
        }

        // ---- two-phase cross-wave reduce (8 partials -> red[0..3]) ----
        f32x4 am[2][2] = {{acc00, acc01}, {acc10, acc11}};
        if (wave < 4) {
#pragma unroll
            for (int m = 0; m < 2; ++m)
#pragma unroll
                for (int n = 0; n < 2; ++n)
#pragma unroll
                    for (int i = 0; i < 4; ++i)
                        red[wave][(m * 16 + lg * 4 + i) * 32 + n * 16 + l15] = am[m][n][i];
        }
        __syncthreads();
        if (wave >= 4) {
#pragma unroll
            for (int m = 0; m < 2; ++m)
#pragma unroll
                for (int n = 0; n < 2; ++n)
#pragma unroll
                    for (int i = 0; i < 4; ++i)
                        red[wave - 4][(m * 16 + lg * 4 + i) * 32 + n * 16 + l15] += am[m][n][i];
        }
        __syncthreads();

        // ---- epilogue: 2 elems/thread; all global stores are sc1 ----
        {
            const int base = er * 32 + ec;
            const float2 r0 = *(const float2*)&red[0][base];
            const float2 r1 = *(const float2*)&red[1][base];
            const float2 r2 = *(const float2*)&red[2][base];
            const float2 r3 = *(const float2*)&red[3][base];
            const float t0 = tanhf(xv.x + r0.x + r1.x + r2.x + r3.x);
            const float t1 = tanhf(xv.y + r0.y + r1.y + r2.y + r3.y);
            store8c(io + po, packf2(t0, t1));
            short h0s, l0s, h1s, l1s;
            split2(t0, h0s, l0s); split2(t1, h1s, l1s);
            const unsigned ph = (unsigned)(unsigned short)h0s | ((unsigned)(unsigned short)h1s << 16);
            const unsigned pl = (unsigned)(unsigned short)l0s | ((unsigned)(unsigned short)l1s << 16);
            __hip_atomic_store((unsigned*)&oH[po], ph, __ATOMIC_RELAXED, __HIP_MEMORY_SCOPE_AGENT);
            __hip_atomic_store((unsigned*)&oL[po], pl, __ATOMIC_RELAXED, __HIP_MEMORY_SCOPE_AGENT);
            if (t == LSEQ - 1)
                store8c(final_state + po, packf2(t0, t1));
        }

        // ---- per-mr-group barrier: RELEASE increment, relaxed spin ----
        if (t != LSEQ - 1) {
            __syncthreads();
            if (tid == 0) {
                // RELEASE: drains this block's sc1 h-stores to the L3
                // coherence point before the counter bump becomes visible.
                __hip_atomic_fetch_add(grp_cnt, 1u, __ATOMIC_RELEASE, __HIP_MEMORY_SCOPE_AGENT);
                const unsigned target = (unsigned)t * 64u;
                while (__hip_atomic_load(grp_cnt, __ATOMIC_RELAXED, __HIP_MEMORY_SCOPE_AGENT) < target)
                    __builtin_amdgcn_s_sleep(2);
            }
            __syncthreads();
        }
    }
}

// ---------------------------------------------------------------------------
extern "C" void kernel_launch(void* const* d_in, const int* in_sizes, int n_in,
                              void* d_out, int out_size, void* d_ws, size_t ws_size,
                              hipStream_t stream) {
    (void)in_sizes; (void)n_in; (void)out_size; (void)ws_size;

    const float* X   = (const float*)d_in[0];
    const float* Wih = (const float*)d_in[1];
    const float* Whh = (const float*)d_in[2];
    const float* b   = (const float*)d_in[3];
    float* out = (float*)d_out;

    char* ws = (char*)d_ws;
    short* WihTh = (short*)(ws);
    short* WihTl = (short*)(ws + (size_t) 8*1024*1024);
    short* WhhTh = (short*)(ws + (size_t)16*1024*1024);
    short* WhhTl = (short*)(ws + (size_t)24*1024*1024);
    short* hA_hi = (short*)(ws + (size_t)32*1024*1024);
    short* hA_lo = (short*)(ws + (size_t)32*1024*1024 + 512*1024);
    short* hB_hi = (short*)(ws + (size_t)33*1024*1024);
    short* hB_lo = (short*)(ws + (size_t)33*1024*1024 + 512*1024);
    unsigned* bar = (unsigned*)(ws + (size_t)34*1024*1024);   // 4 x 64 uints

    hipMemsetAsync(bar, 0, 1024, stream);

    dim3 tg(32, 32);
    transpose_split<<<tg, 256, 0, stream>>>(Wih, WihTh, WihTl);
    transpose_split<<<tg, 256, 0, stream>>>(Whh, WhhTh, WhhTl);

    xp_gemm<<<4096, 256, 0, stream>>>(X, WihTh, WihTl, b, out, hA_hi, hA_lo);

    rnn_scan<<<NBLK, 512, 0, stream>>>(WhhTh, WhhTl, hA_hi, hA_lo, hB_hi, hB_lo,
                                       out, out + (size_t)LSEQ * BH, bar);
}

// Round 9
// 5912.117 us; speedup vs baseline: 1.2734x; 1.2734x over previous
//
#include <hip/hip_runtime.h>
#include <hip/hip_bf16.h>
#include <cmath>

#define LSEQ 256
#define BB   128
#define DD   2048
#define HH   2048
#define BH   (BB*HH)
#define NBLK 256   // persistent scan grid: <= #CUs (256) for guaranteed residency

#define SLOT_SHORTS 524288   // 1 MB per h slot: hi plane 512KB + lo plane 512KB
#define PLANE_SHORTS 262144

typedef __attribute__((ext_vector_type(8))) short short8;   // 8 bf16
typedef __attribute__((ext_vector_type(4))) short short4v;  // 4 bf16
typedef __attribute__((ext_vector_type(4))) float f32x4;

// fp32 -> bf16 hi/lo truncation split; hi*hi + hi*lo + lo*hi ~ 2^-16 rel.
__device__ __forceinline__ void split2(float x, short& hi, short& lo) {
    unsigned u = __float_as_uint(x);
    hi = (short)(u >> 16);
    float r = x - __uint_as_float(u & 0xffff0000u);
    lo = (short)(__float_as_uint(r) >> 16);
}

#define MFMA(a, b, c) __builtin_amdgcn_mfma_f32_16x16x32_bf16((a), (b), (c), 0, 0, 0)

// sc1 (L3-coherent, L2-bypass) 16B load — used only in the fallback path.
__device__ __forceinline__ short8 load_h16(const short* p) {
    unsigned long long u0 = __hip_atomic_load((const unsigned long long*)p,
                                              __ATOMIC_RELAXED, __HIP_MEMORY_SCOPE_AGENT);
    unsigned long long u1 = __hip_atomic_load((const unsigned long long*)(p + 4),
                                              __ATOMIC_RELAXED, __HIP_MEMORY_SCOPE_AGENT);
    union { unsigned long long u[2]; short8 s; } r;
    r.u[0] = u0; r.u[1] = u1;
    return r.s;
}

// 8B sc1 store (write-through toward L3; keeps L2 clean).
__device__ __forceinline__ void store8c(void* p, unsigned long long v) {
    __hip_atomic_store((unsigned long long*)p, v, __ATOMIC_RELAXED, __HIP_MEMORY_SCOPE_AGENT);
}
__device__ __forceinline__ unsigned long long packf2(float a, float b) {
    union { float f[2]; unsigned long long u; } r;
    r.f[0] = a; r.f[1] = b;
    return r.u;
}

// ---------------------------------------------------------------------------
// Prep: W [2048][2048] fp32 (k-major) -> outH/outL [n][k] bf16 planes.
// ---------------------------------------------------------------------------
__global__ __launch_bounds__(256) void transpose_split(const float* __restrict__ W,
                                                       short* __restrict__ outH,
                                                       short* __restrict__ outL) {
    __shared__ float S[64][65];
    const int tid = threadIdx.x;
    const int r0 = blockIdx.x * 64;   // k tile
    const int c0 = blockIdx.y * 64;   // n tile
    const int lr = tid >> 2;          // 0..63
    const int lc = (tid & 3) * 16;
#pragma unroll
    for (int j = 0; j < 4; ++j) {
        f32x4 v = *(const f32x4*)&W[(size_t)(r0 + lr) * DD + c0 + lc + 4*j];
#pragma unroll
        for (int q = 0; q < 4; ++q) S[lr][lc + 4*j + q] = v[q];
    }
    __syncthreads();
    short8 h8[2], l8[2];
#pragma unroll
    for (int j = 0; j < 16; ++j) {
        short h, l;
        split2(S[lc + j][lr], h, l);
        h8[j >> 3][j & 7] = h; l8[j >> 3][j & 7] = l;
    }
    const size_t o = (size_t)(c0 + lr) * DD + r0 + lc;
    *(short8*)&outH[o]     = h8[0];
    *(short8*)&outH[o + 8] = h8[1];
    *(short8*)&outL[o]     = l8[0];
    *(short8*)&outL[o + 8] = l8[1];
}

// ---------------------------------------------------------------------------
// xp = X @ W_ih + b  (split-3 bf16 GEMM). 128x128 tile, 4 waves (2x2).
// rt==0 blocks fuse tanh + h0-plane emit (into ring slot 0, plain stores;
// kernel-boundary coherence publishes them to the scan).
// ---------------------------------------------------------------------------
__global__ __launch_bounds__(256) void xp_gemm(const float* __restrict__ X,
                                               const short* __restrict__ WTh,
                                               const short* __restrict__ WTl,
                                               const float* __restrict__ bias,
                                               float* __restrict__ C,
                                               short* __restrict__ h0H,
                                               short* __restrict__ h0L) {
    __shared__ short Ah_s[128 * 40];
    __shared__ short Al_s[128 * 40];

    const int tid = threadIdx.x, lane = tid & 63, wave = tid >> 6;
    const int l15 = lane & 15, lg = lane >> 4;

    const int gid = blockIdx.x;
    const int rt = ((gid >> 8) << 4) | (gid & 15);
    const int ct = (gid >> 4) & 15;
    const int row0 = rt * 128, col0 = ct * 128;
    const int wm = (wave >> 1) * 64, wn = (wave & 1) * 64;

    const int sr = tid >> 3, sc = (tid & 7) * 4;
    const float* gA = X + (size_t)(row0 + sr) * DD + sc;

    size_t brow[4];
#pragma unroll
    for (int n = 0; n < 4; ++n)
        brow[n] = (size_t)(col0 + wn + n * 16 + l15) * DD + lg * 8;

    f32x4 acc[4][4] = {};

    for (int k0 = 0; k0 < DD; k0 += 32) {
        f32x4 av[4];
        short4v h4[4], l4[4];
#pragma unroll
        for (int i = 0; i < 4; ++i)
            av[i] = *(const f32x4*)(gA + (size_t)(32 * i) * DD + k0);
#pragma unroll
        for (int i = 0; i < 4; ++i)
#pragma unroll
            for (int q = 0; q < 4; ++q) {
                short h, l; split2(av[i][q], h, l);
                h4[i][q] = h; l4[i][q] = l;
            }
        short8 bh[4], bl[4];
#pragma unroll
        for (int n = 0; n < 4; ++n) {
            bh[n] = *(const short8*)&WTh[brow[n] + k0];
            bl[n] = *(const short8*)&WTl[brow[n] + k0];
        }
        __syncthreads();
#pragma unroll
        for (int i = 0; i < 4; ++i) {
            *(short4v*)&Ah_s[(sr + 32 * i) * 40 + sc] = h4[i];
            *(short4v*)&Al_s[(sr + 32 * i) * 40 + sc] = l4[i];
        }
        __syncthreads();
        short8 ah[4], al[4];
#pragma unroll
        for (int m = 0; m < 4; ++m) {
            const int ro = (wm + m * 16 + l15) * 40 + lg * 8;
            ah[m] = *(const short8*)&Ah_s[ro];
            al[m] = *(const short8*)&Al_s[ro];
        }
#pragma unroll
        for (int m = 0; m < 4; ++m)
#pragma unroll
            for (int n = 0; n < 4; ++n) {
                acc[m][n] = MFMA(ah[m], bh[n], acc[m][n]);
                acc[m][n] = MFMA(ah[m], bl[n], acc[m][n]);
                acc[m][n] = MFMA(al[m], bh[n], acc[m][n]);
            }
    }

    float bv[4];
#pragma unroll
    for (int n = 0; n < 4; ++n) bv[n] = bias[col0 + wn + n * 16 + l15];

    if (rt == 0) {
#pragma unroll
        for (int m = 0; m < 4; ++m)
#pragma unroll
            for (int n = 0; n < 4; ++n)
#pragma unroll
                for (int i = 0; i < 4; ++i) {
                    const int row = wm + m * 16 + lg * 4 + i;
                    const int col = col0 + wn + n * 16 + l15;
                    const float t = tanhf(acc[m][n][i] + bv[n]);
                    const size_t o = (size_t)row * HH + col;
                    C[o] = t;
                    short h, l; split2(t, h, l);
                    h0H[o] = h; h0L[o] = l;
                }
    } else {
#pragma unroll
        for (int m = 0; m < 4; ++m)
#pragma unroll
            for (int n = 0; n < 4; ++n)
#pragma unroll
                for (int i = 0; i < 4; ++i) {
                    const int row = row0 + wm + m * 16 + lg * 4 + i;
                    const int col = col0 + wn + n * 16 + l15;
                    C[(size_t)row * HH + col] = acc[m][n][i] + bv[n];
                }
    }
}

// ---------------------------------------------------------------------------
// Persistent scan. FRESH=true (ws >= 288MB): h slots form a 255-deep ring of
// FRESH addresses -> consumers use PLAIN cached loads (first touch fills L2
// from L3, the 32 blocks/XCD sharing rows then hit L2; coalesced dwordx4;
// freely pipelined). No stale-line hazard: each slot is written once (sc1
// stores, drained by the RELEASE counter RMW before visibility) then read
// once at the next step. FRESH=false: exact round-8 behavior (depth-2 ring,
// sc1 loads) as fallback.
// ---------------------------------------------------------------------------
template <bool FRESH>
__global__ __launch_bounds__(512) void rnn_scan(const short* __restrict__ WTh,
                                                const short* __restrict__ WTl,
                                                short* __restrict__ ring,
                                                float* __restrict__ out,
                                                float* __restrict__ final_state,
                                                unsigned* __restrict__ bar) {
    __shared__ short Whi[32 * 2048];    // 128 KB: W-hi strip, swizzled
    __shared__ float red[4][1024];      // 16 KB: cross-wave reduce

    const int tid = threadIdx.x, lane = tid & 63, wave = tid >> 6;
    const int l15 = lane & 15, lg = lane >> 4;
    const int mr = blockIdx.x >> 6, nc = blockIdx.x & 63;
    const int m0 = mr * 32, n0 = nc * 32;
    unsigned* grp_cnt = bar + mr * 64;  // 256B apart per mr group

    // one-time LDS fill of W-hi strip (swizzle: byte ^= (col&7)<<4)
    for (int it = 0; it < 16; ++it) {
        const int ci  = it * 512 + tid;   // 8192 16B-chunks
        const int col = ci >> 8;          // 0..31
        const int kc  = ci & 255;
        const short8 v = *(const short8*)&WTh[(size_t)(n0 + col) * HH + kc * 8];
        const int byte = ((col << 12) + (kc << 4)) ^ ((col & 7) << 4);
        *(short8*)((char*)Whi + byte) = v;
    }
    __syncthreads();

    const size_t a0 = (size_t)(m0 + l15) * HH;
    const size_t a1 = a0 + (size_t)16 * HH;
    const size_t b0 = (size_t)(n0 + l15) * HH;
    const size_t b1 = b0 + (size_t)16 * HH;
    const int kbase = wave * 256 + lg * 8;
    const int colbase0 = l15 << 12,        swz0 = (l15 & 7) << 4;
    const int colbase1 = (16 + l15) << 12, swz1 = (l15 & 7) << 4;

    const int e = tid * 2, er = e >> 5, ec = e & 31;       // epilogue coords
    const size_t po = (size_t)(m0 + er) * HH + n0 + ec;

    for (int t = 1; t < LSEQ; ++t) {
        const int rsl = FRESH ? (t - 1) : ((t - 1) & 1);
        const int wsl = FRESH ? t       : (t & 1);
        const short* hHp = ring + (size_t)rsl * SLOT_SHORTS;
        const short* hLp = hHp + PLANE_SHORTS;
        short* oH = ring + (size_t)wsl * SLOT_SHORTS;
        short* oL = oH + PLANE_SHORTS;
        float* io = out + (size_t)t * BH;

        // ---- phase 1: batch-issue ALL loads (xp, h chunks, W-lo) ----
        const float2 xv = *(const float2*)(io + po);
        short8 AH0[8], AH1[8], AL0[8], AL1[8], BL0[8], BL1[8];
#pragma unroll
        for (int kt = 0; kt < 8; ++kt) {
            const int k = kbase + kt * 32;
            if constexpr (FRESH) {
                AH0[kt] = *(const short8*)&hHp[a0 + k];
                AH1[kt] = *(const short8*)&hHp[a1 + k];
                AL0[kt] = *(const short8*)&hLp[a0 + k];
                AL1[kt] = *(const short8*)&hLp[a1 + k];
            } else {
                AH0[kt] = load_h16(&hHp[a0 + k]);
                AH1[kt] = load_h16(&hHp[a1 + k]);
                AL0[kt] = load_h16(&hLp[a0 + k]);
                AL1[kt] = load_h16(&hLp[a1 + k]);
            }
            BL0[kt] = *(const short8*)&WTl[b0 + k];
            BL1[kt] = *(const short8*)&WTl[b1 + k];
        }

        // ---- phase 2: MFMA chain ----
        f32x4 acc00 = {}, acc01 = {}, acc10 = {}, acc11 = {};
#pragma unroll
        for (int kt = 0; kt < 8; ++kt) {
            const int k = kbase + kt * 32;
            const short8 bh0 = *(const short8*)((const char*)Whi + (colbase0 | ((2 * k) ^ swz0)));
            const short8 bh1 = *(const short8*)((const char*)Whi + (colbase1 | ((2 * k) ^ swz1)));
            acc00 = MFMA(AH0[kt], bh0, acc00); acc00 = MFMA(AH0[kt], BL0[kt], acc00); acc00 = MFMA(AL0[kt], bh0, acc00);
            acc01 = MFMA(AH0[kt], bh1, acc01); acc01 = MFMA(AH0[kt], BL1[kt], acc01); acc01 = MFMA(AL0[kt], bh1, acc01);
            acc10 = MFMA(AH1[kt], bh0, acc10); acc10 = MFMA(AH1[kt], BL0[kt], acc10); acc10 = MFMA(AL1[kt], bh0, acc10);
            acc11 = MFMA(AH1[kt], bh1, acc11); acc11 = MFMA(AH1[kt], BL1[kt], acc11); acc11 = MFMA(AL1[kt], bh1, acc11);
        }

        // ---- two-phase cross-wave reduce (8 partials -> red[0..3]) ----
        f32x4 am[2][2] = {{acc00, acc01}, {acc10, acc11}};
        if (wave < 4) {
#pragma unroll
            for (int m = 0; m < 2; ++m)
#pragma unroll
                for (int n = 0; n < 2; ++n)
#pragma unroll
                    for (int i = 0; i < 4; ++i)
                        red[wave][(m * 16 + lg * 4 + i) * 32 + n * 16 + l15] = am[m][n][i];
        }
        __syncthreads();
        if (wave >= 4) {
#pragma unroll
            for (int m = 0; m < 2; ++m)
#pragma unroll
                for (int n = 0; n < 2; ++n)
#pragma unroll
                    for (int i = 0; i < 4; ++i)
                        red[wave - 4][(m * 16 + lg * 4 + i) * 32 + n * 16 + l15] += am[m][n][i];
        }
        __syncthreads();

        // ---- epilogue: 2 elems/thread; global stores sc1 (L2 stays clean) ----
        {
            const int base = er * 32 + ec;
            const float2 r0 = *(const float2*)&red[0][base];
            const float2 r1 = *(const float2*)&red[1][base];
            const float2 r2 = *(const float2*)&red[2][base];
            const float2 r3 = *(const float2*)&red[3][base];
            const float t0 = tanhf(xv.x + r0.x + r1.x + r2.x + r3.x);
            const float t1 = tanhf(xv.y + r0.y + r1.y + r2.y + r3.y);
            store8c(io + po, packf2(t0, t1));
            if (t != LSEQ - 1) {
                short h0s, l0s, h1s, l1s;
                split2(t0, h0s, l0s); split2(t1, h1s, l1s);
                const unsigned ph = (unsigned)(unsigned short)h0s | ((unsigned)(unsigned short)h1s << 16);
                const unsigned pl = (unsigned)(unsigned short)l0s | ((unsigned)(unsigned short)l1s << 16);
                __hip_atomic_store((unsigned*)&oH[po], ph, __ATOMIC_RELAXED, __HIP_MEMORY_SCOPE_AGENT);
                __hip_atomic_store((unsigned*)&oL[po], pl, __ATOMIC_RELAXED, __HIP_MEMORY_SCOPE_AGENT);
            } else {
                store8c(final_state + po, packf2(t0, t1));
            }
        }

        // ---- per-mr-group barrier: RELEASE increment, relaxed spin ----
        if (t != LSEQ - 1) {
            __syncthreads();
            if (tid == 0) {
                // RELEASE drains this block's sc1 h-stores to the L3
                // coherence point before the counter bump becomes visible.
                __hip_atomic_fetch_add(grp_cnt, 1u, __ATOMIC_RELEASE, __HIP_MEMORY_SCOPE_AGENT);
                const unsigned target = (unsigned)t * 64u;
                while (__hip_atomic_load(grp_cnt, __ATOMIC_RELAXED, __HIP_MEMORY_SCOPE_AGENT) < target)
                    __builtin_amdgcn_s_sleep(2);
            }
            __syncthreads();
        }
    }
}

// ---------------------------------------------------------------------------
extern "C" void kernel_launch(void* const* d_in, const int* in_sizes, int n_in,
                              void* d_out, int out_size, void* d_ws, size_t ws_size,
                              hipStream_t stream) {
    (void)in_sizes; (void)n_in; (void)out_size;

    const float* X   = (const float*)d_in[0];
    const float* Wih = (const float*)d_in[1];
    const float* Whh = (const float*)d_in[2];
    const float* b   = (const float*)d_in[3];
    float* out = (float*)d_out;

    char* ws = (char*)d_ws;
    short* WihTh = (short*)(ws);
    short* WihTl = (short*)(ws + (size_t) 8*1024*1024);
    short* WhhTh = (short*)(ws + (size_t)16*1024*1024);
    short* WhhTl = (short*)(ws + (size_t)24*1024*1024);
    unsigned* bar = (unsigned*)(ws + (size_t)32*1024*1024);   // 4 x 64 uints
    short* ring  = (short*)(ws + (size_t)33*1024*1024);       // h slots, 1MB each

    // fresh ring needs slots 0..254 -> 33MB + 255MB = 288MB
    const bool fresh = ws_size >= (size_t)288 * 1024 * 1024;

    hipMemsetAsync(bar, 0, 1024, stream);

    dim3 tg(32, 32);
    transpose_split<<<tg, 256, 0, stream>>>(Wih, WihTh, WihTl);
    transpose_split<<<tg, 256, 0, stream>>>(Whh, WhhTh, WhhTl);

    // xp GEMM; t=0 blocks also write h0 = tanh(xp[0]) planes into ring slot 0
    xp_gemm<<<4096, 256, 0, stream>>>(X, WihTh, WihTl, b, out,
                                      ring, ring + PLANE_SHORTS);

    if (fresh)
        rnn_scan<true><<<NBLK, 512, 0, stream>>>(WhhTh, WhhTl, ring, out,
                                                 out + (size_t)LSEQ * BH, bar);
    else
        rnn_scan<false><<<NBLK, 512, 0, stream>>>(WhhTh, WhhTl, ring, out,
                                                  out + (size_t)LSEQ * BH, bar);
}